// Round 12
// baseline (87.802 us; speedup 1.0000x reference)
//
#include <hip/hip_runtime.h>
#include <hip/hip_bf16.h>
#include <math.h>
#include <stdint.h>

// DynamicViewSampler — prep (m -> fragment bf16 + per-tile den) +
// GEMM (bf16 MFMA, A from ws, B staged LDS, 2-DEEP register prefetch) +
// reduce (per-(b,v) block, sums den_tile itself).
// Structure = round-8 (best 42.8us); single change in gemm: prefetch depth 2
// so tile t+2's global loads fly under tiles t and t+1 (covers ~900cyc HBM).

constexpr int VV  = 64;    // views (M)
constexpr int DC  = 128;   // D cols per block (N)
constexpr int KS  = 64;    // L rows per tile
constexpr int NTH = 256;
constexpr int ST2 = 134;   // smB row stride in bf16 units (conflict-free gather)
constexpr int KCH = 8;     // chunks per batch

typedef __attribute__((ext_vector_type(8))) short short8;
typedef __attribute__((ext_vector_type(4))) float f32x4;

static __device__ __forceinline__ unsigned short f2bf(float f) {
    __hip_bfloat16 h = __float2bfloat16(f);
    return __builtin_bit_cast(unsigned short, h);
}

// ---------------- prep: m tiles (fragment order) + per-tile den ----------------
__global__ __launch_bounds__(256)
void dvs_prep(const int* __restrict__ v_len, const int* __restrict__ gthw,
              const float* __restrict__ centers,
              unsigned short* __restrict__ mws,     // [B][NT][8][64] short8
              float* __restrict__ den_tile,         // [B][NT][64]
              int NT)
{
    const int t = blockIdx.x, b = blockIdx.y;
    const int Lv = v_len[b];
    const int lt = t * KS;
    if (lt >= Lv) return;

    const float Hf = (float)gthw[b*3 + 1];
    const float Wf = (float)gthw[b*3 + 2];
    const float sq = sqrtf((float)Lv * (Wf / Hf));
    int W_eff = (int)rintf(sq);                       if (W_eff < 1) W_eff = 1;
    int H_eff = (int)ceilf((float)Lv / (float)W_eff); if (H_eff < 1) H_eff = 1;
    const float invW = 1.f / (float)W_eff, invH = 1.f / (float)H_eff;

    const int tid  = threadIdx.x;
    const int lane = tid & 63, wave = tid >> 6;
    const int ar = lane & 15, koct = lane >> 4;

    __shared__ float sden[2][4][VV];

    short8* mtile = (short8*)mws + ((size_t)b * NT + t) * 8 * 64;

#pragma unroll
    for (int i = 0; i < 2; ++i) {
        const int f  = wave * 2 + i;
        const int ks = f >> 2, mf = f & 3;
        const int v  = mf * 16 + ar;
        const float2 ctr = ((const float2*)centers)[(size_t)b * VV + v];

        int l   = lt + ks * 32 + koct * 8;
        int row = l / W_eff;
        int col = l - row * W_eff;
        float y = (float)row * invH;

        union { unsigned short h[8]; short8 s; } ap;
        float ds = 0.f;
#pragma unroll
        for (int j = 0; j < 8; ++j) {
            float m = 0.f;
            if (l + j < Lv) {
                const float x  = (float)col * invW;
                const float dx = ctr.x - x, dy = ctr.y - y;
                m = __expf(-20.f * (dx * dx + dy * dy));
            }
            ds += m;
            ap.h[j] = f2bf(m);
            if (++col == W_eff) { col = 0; ++row; y = (float)row * invH; }
        }
        mtile[f * 64 + lane] = ap.s;
        sden[ks][koct][v] = ds;           // unique (ks,koct,v) per (f,lane)
    }
    __syncthreads();
    if (tid < VV) {
        float s = 0.f;
#pragma unroll
        for (int ks = 0; ks < 2; ++ks)
#pragma unroll
            for (int q = 0; q < 4; ++q) s += sden[ks][q][tid];
        den_tile[((size_t)b * NT + t) * VV + tid] = s;
    }
}

// -------- GEMM: A from ws, B staged LDS with 2-deep register prefetch --------
__global__ __launch_bounds__(NTH)
void dvs_mfma(const float* __restrict__ v_pad, const int* __restrict__ v_len,
              const unsigned short* __restrict__ mws,
              float* __restrict__ num_part,   // [B][KCH][V][D] f32
              int L, int D, int NT)
{
    const int kblk = blockIdx.x, dcb = blockIdx.y, b = blockIdx.z;
    const int Lv = v_len[b];
    const int chunk = (((Lv + KCH - 1) / KCH) + 63) & ~63;   // 64-aligned
    const int l0 = kblk * chunk;
    if (l0 >= Lv) return;
    const int l1 = min(l0 + chunk, Lv);

    const int tid  = threadIdx.x;
    const int d0   = dcb * DC;
    const int lane = tid & 63;
    const int wave = tid >> 6;

    __shared__ __align__(16) unsigned short smB[KS][ST2];   // ~16.75 KB

    const int sd   = tid & 31;    // B-staging: 32 float4 cols
    const int srow = tid >> 5;    //            8 row-groups
    const int fcol = lane & 15, foct = lane >> 4;

    f32x4 acc[4][2];
#pragma unroll
    for (int i = 0; i < 4; ++i) {
        acc[i][0] = f32x4{0.f, 0.f, 0.f, 0.f};
        acc[i][1] = f32x4{0.f, 0.f, 0.f, 0.f};
    }

    const float*  vp_b  = v_pad + (size_t)b * L * D + d0;
    const short8* mws_b = (const short8*)mws + (size_t)b * NT * 8 * 64;

    // 2-deep prefetch registers
    float4 ld[2][8];

#define ISSUE(SET, LT)                                                         \
    _Pragma("unroll")                                                          \
    for (int it = 0; it < 8; ++it) {                                           \
        const int l = (LT) + it * 8 + srow;                                    \
        ld[SET][it] = make_float4(0.f, 0.f, 0.f, 0.f);                         \
        if (l < l1)                                                            \
            ld[SET][it] = *(const float4*)(vp_b + (size_t)l * D + sd * 4);     \
    }

    // prologue: tiles 0 and 1 in flight
    ISSUE(0, l0);
    if (l0 + KS < l1) { ISSUE(1, l0 + KS); }

    int lt = l0, cur = 0;
    for (; lt < l1; lt += KS, cur ^= 1) {
        // ---- stage B from ld[cur] (loads issued 2 tiles ago) ----
#pragma unroll
        for (int it = 0; it < 8; ++it) {
            const int lrow = it * 8 + srow;
            unsigned* w = (unsigned*)&smB[lrow][sd * 4];
            w[0] = (unsigned)f2bf(ld[cur][it].x) | ((unsigned)f2bf(ld[cur][it].y) << 16);
            w[1] = (unsigned)f2bf(ld[cur][it].z) | ((unsigned)f2bf(ld[cur][it].w) << 16);
        }
        __syncthreads();                       // tile staged

        // ---- issue tile t+2's loads (fly under 2 full tile phases) ----
        if (lt + 2 * KS < l1) { ISSUE(cur, lt + 2 * KS); }

        // ---- A fragments: direct coalesced b128 loads from ws (L2/L3) ----
        const short8* mt = mws_b + ((size_t)(lt >> 6)) * 8 * 64;
        short8 af[2][4];
#pragma unroll
        for (int ks = 0; ks < 2; ++ks)
#pragma unroll
            for (int mf = 0; mf < 4; ++mf)
                af[ks][mf] = mt[(ks * 4 + mf) * 64 + lane];

        // ---- MFMA: 2 k-halves x 4 m-frags x 2 n-frags ----
#pragma unroll
        for (int ks = 0; ks < 2; ++ks) {
#pragma unroll
            for (int nf = 0; nf < 2; ++nf) {
                const int colx  = wave * 32 + nf * 16 + fcol;
                const int kbase = ks * 32 + foct * 8;
                union { unsigned short h[8]; short8 s; } bf;
#pragma unroll
                for (int j = 0; j < 8; ++j)
                    bf.h[j] = smB[kbase + j][colx];
#pragma unroll
                for (int mf = 0; mf < 4; ++mf)
                    acc[mf][nf] = __builtin_amdgcn_mfma_f32_16x16x32_bf16(
                        af[ks][mf], bf.s, acc[mf][nf], 0, 0, 0);
            }
        }
        __syncthreads();                       // MFMA reads done; smB reusable
    }
#undef ISSUE

    // ---- numerator partials (C/D: col=lane&15, row=(lane>>4)*4+r) ----
    float* basep = num_part + ((size_t)b * KCH + kblk) * VV * (size_t)D + d0 + wave * 32;
#pragma unroll
    for (int mf = 0; mf < 4; ++mf) {
#pragma unroll
        for (int nf = 0; nf < 2; ++nf) {
            const int colx = nf * 16 + fcol;
            const int row0 = mf * 16 + foct * 4;
#pragma unroll
            for (int r = 0; r < 4; ++r)
                basep[(size_t)(row0 + r) * D + colx] = acc[mf][nf][r];
        }
    }
}

// ---------------- reduce: one block per (b,v); den from den_tile ----------------
__global__ __launch_bounds__(256)
void dvs_reduce(const float* __restrict__ num_part,
                const float* __restrict__ den_tile,
                const int*   __restrict__ v_len,
                float*       __restrict__ out,
                int D, int NT)
{
    const int bv = blockIdx.x;
    const int b  = bv >> 6;
    const int v  = bv & 63;
    const int tid = threadIdx.x;              // d4 index (D/4 = 256)

    const int Lv    = v_len[b];
    const int chunk = (((Lv + KCH - 1) / KCH) + 63) & ~63;
    const int nk    = (Lv + chunk - 1) / chunk;
    const int nt    = (Lv + KS - 1) / KS;

    __shared__ float s64[64];
    __shared__ float sinv;
    if (tid < 64) {
        float s = 0.f;
        for (int t = tid; t < nt; t += 64)
            s += den_tile[((size_t)b * NT + t) * VV + v];
        s64[tid] = s;
    }
    __syncthreads();
    if (tid == 0) {
        float s = 1e-6f;
#pragma unroll
        for (int i = 0; i < 64; ++i) s += s64[i];
        sinv = 1.0f / s;
    }
    __syncthreads();

    float4 num = make_float4(0.f, 0.f, 0.f, 0.f);
    const float* np = num_part + ((size_t)b * KCH * VV + v) * (size_t)D + tid * 4;
    for (int k = 0; k < nk; ++k) {
        const float4 p = *(const float4*)(np + (size_t)k * VV * D);
        num.x += p.x; num.y += p.y; num.z += p.z; num.w += p.w;
    }
    const float inv = sinv;
    *(float4*)(out + (size_t)bv * D + tid * 4) =
        make_float4(num.x * inv, num.y * inv, num.z * inv, num.w * inv);
}

extern "C" void kernel_launch(void* const* d_in, const int* in_sizes, int n_in,
                              void* d_out, int out_size, void* d_ws, size_t ws_size,
                              hipStream_t stream)
{
    const float* v_pad     = (const float*)d_in[0];
    const int*   v_len     = (const int*)d_in[1];
    const int*   grid_thws = (const int*)d_in[2];
    const float* centers   = (const float*)d_in[3];
    float*       out       = (float*)d_out;

    const int B  = in_sizes[1];
    const int D  = out_size / (B * VV);
    const int L  = in_sizes[0] / (B * D);
    const int NT = (L + KS - 1) / KS;

    // workspace layout (all 16B-aligned)
    float*          num_part = (float*)d_ws;                               // B*KCH*V*D f32
    float*          den_tile = num_part + (size_t)B * KCH * VV * D;        // B*NT*V
    unsigned short* mws      = (unsigned short*)(den_tile + (size_t)B * NT * VV);

    dim3 gridP(NT, B);
    dvs_prep<<<gridP, 256, 0, stream>>>(v_len, grid_thws, centers, mws,
                                        den_tile, NT);

    dim3 gridG(KCH, D / DC, B);
    dvs_mfma<<<gridG, NTH, 0, stream>>>(v_pad, v_len, mws, num_part, L, D, NT);

    dvs_reduce<<<B * VV, 256, 0, stream>>>(num_part, den_tile, v_len, out, D, NT);
}

// Round 13
// 45.420 us; speedup vs baseline: 1.9331x; 1.9331x over previous
//
#include <hip/hip_runtime.h>
#include <hip/hip_bf16.h>
#include <math.h>
#include <stdint.h>

// DynamicViewSampler — prep (m -> fragment bf16 + per-tile den) +
// GEMM (bf16 MFMA, A from ws, B staged LDS, 2-deep STATIC-register prefetch) +
// reduce (per-(b,v) block).
// Round-12 lesson (rule #20): ld[cur][it] with runtime cur -> scratch spill,
// 2x slowdown. Fix: named ldA/ldB sets + manually 2x-unrolled ping-pong loop,
// every register index compile-time constant.

constexpr int VV  = 64;    // views (M)
constexpr int DC  = 128;   // D cols per block (N)
constexpr int KS  = 64;    // L rows per tile
constexpr int NTH = 256;
constexpr int ST2 = 134;   // smB row stride in bf16 units (conflict-free gather)
constexpr int KCH = 8;     // chunks per batch

typedef __attribute__((ext_vector_type(8))) short short8;
typedef __attribute__((ext_vector_type(4))) float f32x4;

static __device__ __forceinline__ unsigned short f2bf(float f) {
    __hip_bfloat16 h = __float2bfloat16(f);
    return __builtin_bit_cast(unsigned short, h);
}

// ---------------- prep: m tiles (fragment order) + per-tile den ----------------
__global__ __launch_bounds__(256)
void dvs_prep(const int* __restrict__ v_len, const int* __restrict__ gthw,
              const float* __restrict__ centers,
              unsigned short* __restrict__ mws,     // [B][NT][8][64] short8
              float* __restrict__ den_tile,         // [B][NT][64]
              int NT)
{
    const int t = blockIdx.x, b = blockIdx.y;
    const int Lv = v_len[b];
    const int lt = t * KS;
    if (lt >= Lv) return;

    const float Hf = (float)gthw[b*3 + 1];
    const float Wf = (float)gthw[b*3 + 2];
    const float sq = sqrtf((float)Lv * (Wf / Hf));
    int W_eff = (int)rintf(sq);                       if (W_eff < 1) W_eff = 1;
    int H_eff = (int)ceilf((float)Lv / (float)W_eff); if (H_eff < 1) H_eff = 1;
    const float invW = 1.f / (float)W_eff, invH = 1.f / (float)H_eff;

    const int tid  = threadIdx.x;
    const int lane = tid & 63, wave = tid >> 6;
    const int ar = lane & 15, koct = lane >> 4;

    __shared__ float sden[2][4][VV];

    short8* mtile = (short8*)mws + ((size_t)b * NT + t) * 8 * 64;

#pragma unroll
    for (int i = 0; i < 2; ++i) {
        const int f  = wave * 2 + i;
        const int ks = f >> 2, mf = f & 3;
        const int v  = mf * 16 + ar;
        const float2 ctr = ((const float2*)centers)[(size_t)b * VV + v];

        int l   = lt + ks * 32 + koct * 8;
        int row = l / W_eff;
        int col = l - row * W_eff;
        float y = (float)row * invH;

        union { unsigned short h[8]; short8 s; } ap;
        float ds = 0.f;
#pragma unroll
        for (int j = 0; j < 8; ++j) {
            float m = 0.f;
            if (l + j < Lv) {
                const float x  = (float)col * invW;
                const float dx = ctr.x - x, dy = ctr.y - y;
                m = __expf(-20.f * (dx * dx + dy * dy));
            }
            ds += m;
            ap.h[j] = f2bf(m);
            if (++col == W_eff) { col = 0; ++row; y = (float)row * invH; }
        }
        mtile[f * 64 + lane] = ap.s;
        sden[ks][koct][v] = ds;           // unique (ks,koct,v) per (f,lane)
    }
    __syncthreads();
    if (tid < VV) {
        float s = 0.f;
#pragma unroll
        for (int ks = 0; ks < 2; ++ks)
#pragma unroll
            for (int q = 0; q < 4; ++q) s += sden[ks][q][tid];
        den_tile[((size_t)b * NT + t) * VV + tid] = s;
    }
}

// ---- GEMM: A from ws, B staged LDS, 2-deep static prefetch (ldA/ldB) ----
__global__ __launch_bounds__(NTH)
void dvs_mfma(const float* __restrict__ v_pad, const int* __restrict__ v_len,
              const unsigned short* __restrict__ mws,
              float* __restrict__ num_part,   // [B][KCH][V][D] f32
              int L, int D, int NT)
{
    const int kblk = blockIdx.x, dcb = blockIdx.y, b = blockIdx.z;
    const int Lv = v_len[b];
    const int chunk = (((Lv + KCH - 1) / KCH) + 63) & ~63;   // 64-aligned
    const int l0 = kblk * chunk;
    if (l0 >= Lv) return;
    const int l1 = min(l0 + chunk, Lv);

    const int tid  = threadIdx.x;
    const int d0   = dcb * DC;
    const int lane = tid & 63;
    const int wave = tid >> 6;

    __shared__ __align__(16) unsigned short smB[KS][ST2];   // ~16.75 KB

    const int sd   = tid & 31;    // B-staging: 32 float4 cols
    const int srow = tid >> 5;    //            8 row-groups
    const int fcol = lane & 15, foct = lane >> 4;

    f32x4 acc[4][2];
#pragma unroll
    for (int i = 0; i < 4; ++i) {
        acc[i][0] = f32x4{0.f, 0.f, 0.f, 0.f};
        acc[i][1] = f32x4{0.f, 0.f, 0.f, 0.f};
    }

    const float*  vp_b  = v_pad + (size_t)b * L * D + d0;
    const short8* mws_b = (const short8*)mws + (size_t)b * NT * 8 * 64;

    float4 ldA[8], ldB[8];                    // named sets: static indexing only

#define ISSUE(SET, LT)                                                         \
    _Pragma("unroll")                                                          \
    for (int it = 0; it < 8; ++it) {                                           \
        const int l = (LT) + it * 8 + srow;                                    \
        SET[it] = make_float4(0.f, 0.f, 0.f, 0.f);                             \
        if (l < l1)                                                            \
            SET[it] = *(const float4*)(vp_b + (size_t)l * D + sd * 4);         \
    }

#define STAGE(SET)                                                             \
    _Pragma("unroll")                                                          \
    for (int it = 0; it < 8; ++it) {                                           \
        const int lrow = it * 8 + srow;                                        \
        unsigned* w = (unsigned*)&smB[lrow][sd * 4];                           \
        w[0] = (unsigned)f2bf(SET[it].x) | ((unsigned)f2bf(SET[it].y) << 16);  \
        w[1] = (unsigned)f2bf(SET[it].z) | ((unsigned)f2bf(SET[it].w) << 16);  \
    }

#define MFMA_TILE(LT)                                                          \
    {                                                                          \
        const short8* mt = mws_b + ((size_t)((LT) >> 6)) * 8 * 64;             \
        short8 af[2][4];                                                       \
        _Pragma("unroll")                                                      \
        for (int ks = 0; ks < 2; ++ks)                                         \
            _Pragma("unroll")                                                  \
            for (int mf = 0; mf < 4; ++mf)                                     \
                af[ks][mf] = mt[(ks * 4 + mf) * 64 + lane];                    \
        _Pragma("unroll")                                                      \
        for (int ks = 0; ks < 2; ++ks) {                                       \
            _Pragma("unroll")                                                  \
            for (int nf = 0; nf < 2; ++nf) {                                   \
                const int colx  = wave * 32 + nf * 16 + fcol;                  \
                const int kbase = ks * 32 + foct * 8;                          \
                union { unsigned short h[8]; short8 s; } bf;                   \
                _Pragma("unroll")                                              \
                for (int j = 0; j < 8; ++j)                                    \
                    bf.h[j] = smB[kbase + j][colx];                            \
                _Pragma("unroll")                                              \
                for (int mf = 0; mf < 4; ++mf)                                 \
                    acc[mf][nf] = __builtin_amdgcn_mfma_f32_16x16x32_bf16(     \
                        af[ks][mf], bf.s, acc[mf][nf], 0, 0, 0);               \
            }                                                                  \
        }                                                                      \
    }

    // prologue: tiles 0 and 1 in flight
    ISSUE(ldA, l0);
    if (l0 + KS < l1) { ISSUE(ldB, l0 + KS); }

    // ping-pong loop, manually 2x unrolled (static register sets)
    int lt = l0;
    for (;;) {
        STAGE(ldA);
        __syncthreads();
        if (lt + 2 * KS < l1) { ISSUE(ldA, lt + 2 * KS); }
        MFMA_TILE(lt);
        __syncthreads();
        lt += KS; if (lt >= l1) break;

        STAGE(ldB);
        __syncthreads();
        if (lt + 2 * KS < l1) { ISSUE(ldB, lt + 2 * KS); }
        MFMA_TILE(lt);
        __syncthreads();
        lt += KS; if (lt >= l1) break;
    }

#undef ISSUE
#undef STAGE
#undef MFMA_TILE

    // ---- numerator partials (C/D: col=lane&15, row=(lane>>4)*4+r) ----
    float* basep = num_part + ((size_t)b * KCH + kblk) * VV * (size_t)D + d0 + wave * 32;
#pragma unroll
    for (int mf = 0; mf < 4; ++mf) {
#pragma unroll
        for (int nf = 0; nf < 2; ++nf) {
            const int colx = nf * 16 + fcol;
            const int row0 = mf * 16 + foct * 4;
#pragma unroll
            for (int r = 0; r < 4; ++r)
                basep[(size_t)(row0 + r) * D + colx] = acc[mf][nf][r];
        }
    }
}

// ---------------- reduce: one block per (b,v); den from den_tile ----------------
__global__ __launch_bounds__(256)
void dvs_reduce(const float* __restrict__ num_part,
                const float* __restrict__ den_tile,
                const int*   __restrict__ v_len,
                float*       __restrict__ out,
                int D, int NT)
{
    const int bv = blockIdx.x;
    const int b  = bv >> 6;
    const int v  = bv & 63;
    const int tid = threadIdx.x;              // d4 index (D/4 = 256)

    const int Lv    = v_len[b];
    const int chunk = (((Lv + KCH - 1) / KCH) + 63) & ~63;
    const int nk    = (Lv + chunk - 1) / chunk;
    const int nt    = (Lv + KS - 1) / KS;

    __shared__ float s64[64];
    __shared__ float sinv;
    if (tid < 64) {
        float s = 0.f;
        for (int t = tid; t < nt; t += 64)
            s += den_tile[((size_t)b * NT + t) * VV + v];
        s64[tid] = s;
    }
    __syncthreads();
    if (tid == 0) {
        float s = 1e-6f;
#pragma unroll
        for (int i = 0; i < 64; ++i) s += s64[i];
        sinv = 1.0f / s;
    }
    __syncthreads();

    float4 num = make_float4(0.f, 0.f, 0.f, 0.f);
    const float* np = num_part + ((size_t)b * KCH * VV + v) * (size_t)D + tid * 4;
    for (int k = 0; k < nk; ++k) {
        const float4 p = *(const float4*)(np + (size_t)k * VV * D);
        num.x += p.x; num.y += p.y; num.z += p.z; num.w += p.w;
    }
    const float inv = sinv;
    *(float4*)(out + (size_t)bv * D + tid * 4) =
        make_float4(num.x * inv, num.y * inv, num.z * inv, num.w * inv);
}

extern "C" void kernel_launch(void* const* d_in, const int* in_sizes, int n_in,
                              void* d_out, int out_size, void* d_ws, size_t ws_size,
                              hipStream_t stream)
{
    const float* v_pad     = (const float*)d_in[0];
    const int*   v_len     = (const int*)d_in[1];
    const int*   grid_thws = (const int*)d_in[2];
    const float* centers   = (const float*)d_in[3];
    float*       out       = (float*)d_out;

    const int B  = in_sizes[1];
    const int D  = out_size / (B * VV);
    const int L  = in_sizes[0] / (B * D);
    const int NT = (L + KS - 1) / KS;

    // workspace layout (all 16B-aligned)
    float*          num_part = (float*)d_ws;                               // B*KCH*V*D f32
    float*          den_tile = num_part + (size_t)B * KCH * VV * D;        // B*NT*V
    unsigned short* mws      = (unsigned short*)(den_tile + (size_t)B * NT * VV);

    dim3 gridP(NT, B);
    dvs_prep<<<gridP, 256, 0, stream>>>(v_len, grid_thws, centers, mws,
                                        den_tile, NT);

    dim3 gridG(KCH, D / DC, B);
    dvs_mfma<<<gridG, NTH, 0, stream>>>(v_pad, v_len, mws, num_part, L, D, NT);

    dvs_reduce<<<B * VV, 256, 0, stream>>>(num_part, den_tile, v_len, out, D, NT);
}